// Round 4
// baseline (673.616 us; speedup 1.0000x reference)
//
#include <hip/hip_runtime.h>
#include <math.h>

#define NPIX 262144   // 512*512
#define FSTR 513      // LDS column stride for batch-8 FFT (pad 512+1)

typedef __attribute__((ext_vector_type(2))) float v2f;

// ---------------------------------------------------------------------------
// Complex-packing scheme: 24 real images -> 12 packed complex images.
//   p in [0,8):  z = x[b=p, c=0] + i * x[b=p, c=1]   (same per-batch mask!)
//   p in [8,12): k=p-8, z = x[b=2k, c=2] + i * x[b=2k+1, c=2] (masks differ)
// Forward 2D FFT, modulation, inverse 2D FFT all operate on packed z:
//   - pairs p<8: masked spectrum = m (.) Z  (mask identical for Re/Im parts)
//   - pairs p>=8: W[k] = 0.5[(ma+mb) Z[k] + (ma-mb) conj(Z[-k])] (Hermitian)
//   - lowpass_A = clip(Re(ifft W)), lowpass_B = clip(Im(ifft W))
//   - xmag needs explicit Hermitian unpack -> separate k_xmag kernel.
// ---------------------------------------------------------------------------

__device__ __forceinline__ int brev9(int i) { return (int)(__brev((unsigned)i) >> 23); }

__device__ __forceinline__ void init_tw(float* twr, float* twi, int t) {
  if (t < 256) {
    float ang = -3.14159265358979323846f * (float)t / 256.0f;
    float s, c;
    sincosf(ang, &s, &c);
    twr[t] = c; twi[t] = s;
  }
}

// 8 x 512-pt FFTs in LDS, column-major: element p of FFT c at [c*FSTR + p].
// Radix-4 core, final radix-2 stage. Input stored radix-2 bit-reversed.
template<bool FWD>
__device__ __forceinline__ void fft512x8(float* __restrict__ sr, float* __restrict__ si,
                                         const float* __restrict__ twr,
                                         const float* __restrict__ twi, int t) {
  const int c  = t >> 5;
  const int tq = t & 31;
  float* cr = sr + c * FSTR;
  float* ci = si + c * FSTR;
  #pragma unroll
  for (int sp = 0; sp < 4; sp++) {
    const int s = 2 * sp;
    const int h = 1 << s;
    __syncthreads();
    #pragma unroll
    for (int m = 0; m < 4; m++) {
      int q = tq + 32 * m;                    // quad id 0..127
      int j = q & (h - 1);
      int base = ((q >> s) << (s + 2)) | j;
      int i1 = j << (8 - s);                  // stage-s twiddle
      int i2 = j << (7 - s);                  // stage-(s+1) twiddle
      float w1r = twr[i1], w1i = FWD ? twi[i1] : -twi[i1];
      float w2r = twr[i2], w2i = FWD ? twi[i2] : -twi[i2];
      float ar = cr[base],         ai = ci[base];
      float br = cr[base + h],     bi = ci[base + h];
      float c2r = cr[base + 2*h],  c2i = ci[base + 2*h];
      float dr = cr[base + 3*h],   di = ci[base + 3*h];
      // stage s
      float wbr = br * w1r - bi * w1i, wbi = br * w1i + bi * w1r;
      float wdr = dr * w1r - di * w1i, wdi = dr * w1i + di * w1r;
      float t0r = ar + wbr,  t0i = ai + wbi;
      float t1r = ar - wbr,  t1i = ai - wbi;
      float t2r = c2r + wdr, t2i = c2i + wdi;
      float t3r = c2r - wdr, t3i = c2i - wdi;
      // stage s+1 ; w2' = w2 * (-i) fwd, (+i) inv
      float u2r = t2r * w2r - t2i * w2i, u2i = t2r * w2i + t2i * w2r;
      float v3r = t3r * w2r - t3i * w2i, v3i = t3r * w2i + t3i * w2r;
      float u3r = FWD ? v3i : -v3i;
      float u3i = FWD ? -v3r : v3r;
      cr[base]         = t0r + u2r;  ci[base]         = t0i + u2i;
      cr[base + 2*h]   = t0r - u2r;  ci[base + 2*h]   = t0i - u2i;
      cr[base + h]     = t1r + u3r;  ci[base + h]     = t1i + u3i;
      cr[base + 3*h]   = t1r - u3r;  ci[base + 3*h]   = t1i - u3i;
    }
  }
  // final radix-2 stage (s=8, half=256)
  __syncthreads();
  #pragma unroll
  for (int m = 0; m < 8; m++) {
    int k = tq + 32 * m;                      // 0..255 == j
    float wr = twr[k], wi = FWD ? twi[k] : -twi[k];
    float vr = cr[k + 256], vi = ci[k + 256];
    float tr = vr * wr - vi * wi;
    float ti = vr * wi + vi * wr;
    float ur = cr[k], ui = ci[k];
    cr[k] = ur + tr;        ci[k] = ui + ti;
    cr[k + 256] = ur - tr;  ci[k + 256] = ui - ti;
  }
  __syncthreads();
}

// pair tables (device-side from p)
__device__ __forceinline__ void pair_src(int p, int& ia, int& ib) {
  if (p < 8) { ia = 3 * p; ib = 3 * p + 1; }
  else { int k = p - 8; ia = 6 * k + 2; ib = 6 * k + 5; }
}

// forward FFT over 8 contiguous rows per block; packs two real images.
__global__ __launch_bounds__(256) void k_fft_rows(const float* __restrict__ x,
                                                  float2* __restrict__ xf) {
  __shared__ float sr[8 * FSTR], si[8 * FSTR], twr[256], twi[256];
  int t = threadIdx.x;
  int p = blockIdx.x >> 6;
  int r0 = (blockIdx.x & 63) << 3;
  init_tw(twr, twi, t);
  int ia, ib;
  pair_src(p, ia, ib);
  const float4* pa = (const float4*)(x + (size_t)ia * NPIX + (size_t)r0 * 512);
  const float4* pb = (const float4*)(x + (size_t)ib * NPIX + (size_t)r0 * 512);
  for (int e = t; e < 1024; e += 256) {
    int row = e >> 7, w = e & 127;
    float4 fa = pa[e];
    float4 fb = pb[e];
    float* cr = sr + row * FSTR;
    float* ci = si + row * FSTR;
    int pc = 4 * w;
    cr[brev9(pc)]     = fa.x;  ci[brev9(pc)]     = fb.x;
    cr[brev9(pc + 1)] = fa.y;  ci[brev9(pc + 1)] = fb.y;
    cr[brev9(pc + 2)] = fa.z;  ci[brev9(pc + 2)] = fb.z;
    cr[brev9(pc + 3)] = fa.w;  ci[brev9(pc + 3)] = fb.w;
  }
  fft512x8<true>(sr, si, twr, twi, t);
  float4* q4 = (float4*)(xf + (size_t)p * NPIX + (size_t)r0 * 512);
  for (int e = t; e < 2048; e += 256) {
    int row = e >> 8, u = e & 255;
    const float* cr = sr + row * FSTR;
    const float* ci = si + row * FSTR;
    q4[e] = make_float4(cr[2 * u], ci[2 * u], cr[2 * u + 1], ci[2 * u + 1]);
  }
}

// forward FFT over 8 adjacent columns per block (in-place on packed xf).
__global__ __launch_bounds__(256) void k_fft_cols(float2* __restrict__ xf) {
  __shared__ float sr[8 * FSTR], si[8 * FSTR], twr[256], twi[256];
  int t = threadIdx.x;
  int p = blockIdx.x >> 6;
  int c0 = (blockIdx.x & 63) << 3;
  init_tw(twr, twi, t);
  float2* base = xf + (size_t)p * NPIX + c0;
  const int q = t & 3;
  const int j = (t >> 2) & 15;
  const int w = t >> 6;
  #pragma unroll
  for (int it = 0; it < 8; it++) {
    int row = 32 * j + 4 * it + w;           // stride-32 row set
    float4 f = *(const float4*)(base + (size_t)row * 512 + 2 * q);
    int rr = brev9(row);
    sr[(2 * q) * FSTR + rr]     = f.x;  si[(2 * q) * FSTR + rr]     = f.y;
    sr[(2 * q + 1) * FSTR + rr] = f.z;  si[(2 * q + 1) * FSTR + rr] = f.w;
  }
  fft512x8<true>(sr, si, twr, twi, t);
  const int rg = t >> 2;                     // 0..63
  #pragma unroll
  for (int it = 0; it < 8; it++) {
    int row = 64 * it + rg;                  // consecutive row set
    float a0 = sr[(2 * q) * FSTR + row],     b0 = si[(2 * q) * FSTR + row];
    float a1 = sr[(2 * q + 1) * FSTR + row], b1 = si[(2 * q + 1) * FSTR + row];
    *(float4*)(base + (size_t)row * 512 + 2 * q) = make_float4(a0, b0, a1, b1);
  }
}

// Hermitian unpack of packed spectra -> log-magnitudes for both components,
// scattered to the fftshift-remapped xmag slots (batch +4, channel +1, and
// spatial ^256 shift) that conv1 consumes.
__global__ __launch_bounds__(256) void k_xmag(const float2* __restrict__ xf,
                                              float* __restrict__ xmag) {
  int t = threadIdx.x;
  int p = blockIdx.x >> 6;
  int r0 = (blockIdx.x & 63) << 3;
  int da, db;
  if (p < 8) {
    int bs = (p + 4) & 7;
    da = bs * 3 + 1;                 // (b,0) -> slot (b+4, 1)
    db = bs * 3 + 2;                 // (b,1) -> slot (b+4, 2)
  } else {
    int k = p - 8;
    da = ((2 * k + 4) & 7) * 3;      // (2k,2)   -> slot (2k+4, 0)
    db = ((2 * k + 5) & 7) * 3;      // (2k+1,2) -> slot (2k+5, 0)
  }
  const float2* Z = xf + (size_t)p * NPIX;
  float* A = xmag + (size_t)da * NPIX;
  float* B = xmag + (size_t)db * NPIX;
  for (int e = t; e < 2048; e += 256) {
    int row = r0 + (e >> 8);
    int c0 = (e & 255) * 2;
    float4 z01 = *(const float4*)(Z + (size_t)row * 512 + c0);
    int mr = (512 - row) & 511;
    float2 zm0 = Z[(size_t)mr * 512 + ((512 - c0) & 511)];
    float2 zm1 = Z[(size_t)mr * 512 + (511 - c0)];
    // X_A = (Z + conj(Zm))/2 ; |X_B| = |Z - conj(Zm)|/2
    float ar0 = 0.5f * (z01.x + zm0.x), ai0 = 0.5f * (z01.y - zm0.y);
    float br0 = 0.5f * (z01.x - zm0.x), bi0 = 0.5f * (z01.y + zm0.y);
    float ar1 = 0.5f * (z01.z + zm1.x), ai1 = 0.5f * (z01.w - zm1.y);
    float br1 = 0.5f * (z01.z - zm1.x), bi1 = 0.5f * (z01.w + zm1.y);
    float ma0 = log10f(sqrtf(ar0 * ar0 + ai0 * ai0) + 1.0f);
    float ma1 = log10f(sqrtf(ar1 * ar1 + ai1 * ai1) + 1.0f);
    float mb0 = log10f(sqrtf(br0 * br0 + bi0 * bi0) + 1.0f);
    float mb1 = log10f(sqrtf(br1 * br1 + bi1 * bi1) + 1.0f);
    size_t off = (size_t)(row ^ 256) * 512 + (c0 ^ 256);
    *(float2*)(A + off) = make_float2(ma0, ma1);
    *(float2*)(B + off) = make_float2(mb0, mb1);
  }
}

// conv1: 6->16, 512x512, pad1, relu, 2x2 avgpool -> [b][16][256][256]
// grid (4, 32, 16). Double-buffered LDS, prefetch DISTANCE 2 (loads for ic+2
// issued at top of iter ic; two register queues ldA/ldB, static indexing).
// Packed-fp32 FMA inner loop.
__global__ __launch_bounds__(256) void k_conv1(const float* __restrict__ x,
                                               const float* __restrict__ xmag,
                                               const float* __restrict__ w1,
                                               const float* __restrict__ b1,
                                               float* __restrict__ out) {
  __shared__ float tile[2][18 * 132 + 8];
  const int t = threadIdx.x;
  const int tx = t & 31, ty = t >> 5;
  const int PC0 = blockIdx.x * 64;
  const int PR0 = blockIdx.y * 8;
  const int b  = blockIdx.z >> 1;
  const int og = (blockIdx.z & 1) * 8;
  const int R0 = PR0 * 2 - 1;
  const int C0 = PC0 * 2 - 1;

  int li[10], gi[10];
  bool okf[10];
  #pragma unroll
  for (int k = 0; k < 10; k++) {
    int e = t + 256 * k;
    bool valid = e < 2340;
    int i = e / 130, j = e - i * 130;
    int rr = R0 + i, cc = C0 + j;
    bool ok = valid && ((unsigned)rr < 512u) && ((unsigned)cc < 512u);
    li[k] = valid ? (i * 132 + j) : (18 * 132);
    gi[k] = ok ? (rr * 512 + cc) : 0;
    okf[k] = ok;
  }

  v2f acc[8][4];
  #pragma unroll
  for (int o = 0; o < 8; o++)
    #pragma unroll
    for (int q = 0; q < 4; q++) acc[o][q] = (v2f){0.0f, 0.0f};

  const float* xb = x + (size_t)(b * 3) * NPIX;
  const float* mb = xmag + (size_t)(b * 3) * NPIX;

  // channel source for ic in [0,6)
  auto chan = [&](int ic) -> const float* {
    return (ic < 3) ? (xb + (size_t)ic * NPIX) : (mb + (size_t)(ic - 3) * NPIX);
  };
  auto LOADQ = [&](float* ldq, int ic) {
    const float* sn = chan(ic);
    #pragma unroll
    for (int k = 0; k < 10; k++) ldq[k] = okf[k] ? sn[gi[k]] : 0.0f;
  };
  auto STOREQ = [&](const float* ldq, int bsel) {
    float* nxt = tile[bsel];
    #pragma unroll
    for (int k = 0; k < 10; k++) nxt[li[k]] = ldq[k];
  };
  auto COMPUTE = [&](int bsel, int ic) {
    const float* cur = tile[bsel];
    float patch[4][6];
    #pragma unroll
    for (int dy = 0; dy < 4; dy++) {
      const float* rp = cur + (2 * ty + dy) * 132 + 4 * tx;
      float4 f = *(const float4*)rp;
      float2 g = *(const float2*)(rp + 4);
      patch[dy][0] = f.x; patch[dy][1] = f.y; patch[dy][2] = f.z;
      patch[dy][3] = f.w; patch[dy][4] = g.x; patch[dy][5] = g.y;
    }
    v2f pr[4][5];
    #pragma unroll
    for (int dy = 0; dy < 4; dy++)
      #pragma unroll
      for (int s = 0; s < 5; s++)
        pr[dy][s] = (v2f){patch[dy][s], patch[dy][s + 1]};
    #pragma unroll
    for (int o = 0; o < 8; o++) {
      const float* wk = w1 + (size_t)((og + o) * 6 + ic) * 9;
      #pragma unroll
      for (int dy = 0; dy < 3; dy++)
        #pragma unroll
        for (int kc = 0; kc < 3; kc++) {
          float kw = wk[dy * 3 + kc];
          v2f wv = (v2f){kw, kw};
          acc[o][0] += wv * pr[dy][kc];
          acc[o][1] += wv * pr[dy][kc + 2];
          acc[o][2] += wv * pr[dy + 1][kc];
          acc[o][3] += wv * pr[dy + 1][kc + 2];
        }
    }
  };

  float ldA[10], ldB[10];
  LOADQ(ldA, 0);
  STOREQ(ldA, 0);
  LOADQ(ldA, 1);          // ic=1 in flight across barrier
  __syncthreads();

  #pragma unroll
  for (int ict = 0; ict < 6; ict += 2) {
    // even iter: ic = ict (buffer 0); ldA holds ic+1
    if (ict + 2 < 6) LOADQ(ldB, ict + 2);
    COMPUTE(0, ict);
    STOREQ(ldA, 1);
    __syncthreads();
    // odd iter: ic = ict+1 (buffer 1); ldB holds ic+2 (if any)
    if (ict + 3 < 6) LOADQ(ldA, ict + 3);
    COMPUTE(1, ict + 1);
    if (ict + 2 < 6) {
      STOREQ(ldB, 0);
      __syncthreads();
    }
  }

  #pragma unroll
  for (int o = 0; o < 8; o++) {
    float bias = b1[og + o];
    float p0 = fmaxf(acc[o][0].x + bias, 0.0f) + fmaxf(acc[o][0].y + bias, 0.0f)
             + fmaxf(acc[o][2].x + bias, 0.0f) + fmaxf(acc[o][2].y + bias, 0.0f);
    float p1 = fmaxf(acc[o][1].x + bias, 0.0f) + fmaxf(acc[o][1].y + bias, 0.0f)
             + fmaxf(acc[o][3].x + bias, 0.0f) + fmaxf(acc[o][3].y + bias, 0.0f);
    float2* q = (float2*)(out + ((size_t)(b * 16 + og + o) * 256 + PR0 + ty) * 256 + PC0 + 2 * tx);
    *q = make_float2(p0 * 0.25f, p1 * 0.25f);
  }
}

// conv2: 16->32, 256x256, pad1, relu, pool -> 9 stats per (b,oc) -> S[b][32][9].
// grid (4, 16, 32), og=8 per block; packed-fp32 inner loop; prefetch
// DISTANCE 2 (ldA/ldB register queues) to cover the ~500-900cyc miss latency
// that capped VALUBusy at 47%.
__global__ __launch_bounds__(256) void k_conv2(const float* __restrict__ in,
                                               const float* __restrict__ w2,
                                               const float* __restrict__ b2,
                                               float* __restrict__ S) {
  __shared__ float tile[2][18 * 68 + 8];
  __shared__ float wsum[4][8];
  const int t = threadIdx.x;
  const int tx = t & 31, ty = t >> 5;
  const int bx = blockIdx.x, by = blockIdx.y;
  const int PC0 = bx * 32;
  const int PR0 = by * 8;
  const int b  = blockIdx.z >> 2;
  const int og = (blockIdx.z & 3) * 8;
  const int R0 = PR0 * 2 - 1;
  const int C0 = PC0 * 2 - 1;

  int li[5], gi[5];
  bool okf[5];
  #pragma unroll
  for (int k = 0; k < 5; k++) {
    int e = t + 256 * k;
    bool valid = e < 1188;
    int i = e / 66, j = e - 66 * i;
    int rr = R0 + i, cc = C0 + j;
    bool ok = valid && ((unsigned)rr < 256u) && ((unsigned)cc < 256u);
    li[k] = valid ? (i * 68 + j) : (18 * 68);
    gi[k] = ok ? (rr * 256 + cc) : 0;
    okf[k] = ok;
  }

  v2f acc[8][2];
  #pragma unroll
  for (int o = 0; o < 8; o++) {
    acc[o][0] = (v2f){0.0f, 0.0f};
    acc[o][1] = (v2f){0.0f, 0.0f};
  }

  const float* inb = in + (size_t)(b * 16) * 65536;

  auto LOADQ = [&](float* ldq, int ic) {
    const float* sn = inb + (size_t)ic * 65536;
    #pragma unroll
    for (int k = 0; k < 5; k++) ldq[k] = okf[k] ? sn[gi[k]] : 0.0f;
  };
  auto STOREQ = [&](const float* ldq, int bsel) {
    float* nxt = tile[bsel];
    #pragma unroll
    for (int k = 0; k < 5; k++) nxt[li[k]] = ldq[k];
  };
  auto COMPUTE = [&](int bsel, int ic) {
    const float* cur = tile[bsel];
    float patch[4][4];
    #pragma unroll
    for (int dy = 0; dy < 4; dy++) {
      const float* rp = cur + (2 * ty + dy) * 68 + 2 * tx;
      float2 f0 = *(const float2*)rp;
      float2 f1 = *(const float2*)(rp + 2);
      patch[dy][0] = f0.x; patch[dy][1] = f0.y;
      patch[dy][2] = f1.x; patch[dy][3] = f1.y;
    }
    v2f pr[4][3];
    #pragma unroll
    for (int dy = 0; dy < 4; dy++) {
      pr[dy][0] = (v2f){patch[dy][0], patch[dy][1]};
      pr[dy][1] = (v2f){patch[dy][1], patch[dy][2]};
      pr[dy][2] = (v2f){patch[dy][2], patch[dy][3]};
    }
    #pragma unroll
    for (int o = 0; o < 8; o++) {
      const float* wk = w2 + (size_t)((og + o) * 16 + ic) * 9;
      #pragma unroll
      for (int dy = 0; dy < 3; dy++)
        #pragma unroll
        for (int kc = 0; kc < 3; kc++) {
          float kw = wk[dy * 3 + kc];
          v2f wv = (v2f){kw, kw};
          acc[o][0] += wv * pr[dy][kc];
          acc[o][1] += wv * pr[dy + 1][kc];
        }
    }
  };

  float ldA[5], ldB[5];
  LOADQ(ldA, 0);
  STOREQ(ldA, 0);
  LOADQ(ldA, 1);          // ic=1 in flight across barrier
  __syncthreads();

  #pragma unroll
  for (int ict = 0; ict < 16; ict += 2) {
    // even iter: ic = ict (buffer 0); ldA holds ic+1
    if (ict + 2 < 16) LOADQ(ldB, ict + 2);
    COMPUTE(0, ict);
    STOREQ(ldA, 1);
    __syncthreads();
    // odd iter: ic = ict+1 (buffer 1); ldB holds ic+2 (if any)
    if (ict + 3 < 16) LOADQ(ldA, ict + 3);
    COMPUTE(1, ict + 1);
    if (ict + 2 < 16) {
      STOREQ(ldB, 0);
      __syncthreads();
    }
  }

  const int lane = t & 63;
  const int wid = t >> 6;
  float* Sb0 = S + (size_t)(b * 32 + og) * 9;
  #pragma unroll
  for (int o = 0; o < 8; o++) {
    float bias = b2[og + o];
    float v = (fmaxf(acc[o][0].x + bias, 0.0f) + fmaxf(acc[o][0].y + bias, 0.0f)
             + fmaxf(acc[o][1].x + bias, 0.0f) + fmaxf(acc[o][1].y + bias, 0.0f)) * 0.25f;
    float* Sb = Sb0 + o * 9;
    float ts = v;
    #pragma unroll
    for (int off = 32; off > 0; off >>= 1) ts += __shfl_down(ts, off);
    if (lane == 0) wsum[wid][o] = ts;
    if (by == 0) {
      float e = (ty == 0) ? v : 0.0f;
      #pragma unroll
      for (int off = 32; off > 0; off >>= 1) e += __shfl_down(e, off);
      if (lane == 0) atomicAdd(&Sb[1], e);
    }
    if (by == 15) {
      float e = (ty == 7) ? v : 0.0f;
      #pragma unroll
      for (int off = 32; off > 0; off >>= 1) e += __shfl_down(e, off);
      if (lane == 0) atomicAdd(&Sb[2], e);
    }
    if (bx == 0 && tx == 0)  atomicAdd(&Sb[3], v);
    if (bx == 3 && tx == 31) atomicAdd(&Sb[4], v);
    if (bx == 0 && by == 0  && t == 0)   Sb[5] = v;
    if (bx == 3 && by == 0  && t == 31)  Sb[6] = v;
    if (bx == 0 && by == 15 && t == 224) Sb[7] = v;
    if (bx == 3 && by == 15 && t == 255) Sb[8] = v;
  }
  __syncthreads();
  if (t < 8)
    atomicAdd(&Sb0[t * 9], wsum[0][t] + wsum[1][t] + wsum[2][t] + wsum[3][t]);
}

// k_fc: stats -> conv3-mean (matvec over 288 window sums) -> FC1 -> FC2 -> leaky.
__global__ __launch_bounds__(256) void k_fc(const float* __restrict__ S,
                                            const float* __restrict__ w3,
                                            const float* __restrict__ b3,
                                            const float* __restrict__ fw1,
                                            const float* __restrict__ fb1,
                                            const float* __restrict__ fw2,
                                            const float* __restrict__ fb2,
                                            float* __restrict__ vs_out) {
  __shared__ float Sp[2304];
  __shared__ float y[512];
  __shared__ float h1[2048];
  int t = threadIdx.x;
  for (int e = t; e < 2304; e += 256) {
    int cell = e / 9, k = e - 9 * cell;
    int dy = k / 3, dx = k - 3 * dy;
    const float* s = S + cell * 9;
    float v = s[0];
    if (dy == 0) v -= s[2];
    if (dy == 2) v -= s[1];
    if (dx == 0) v -= s[4];
    if (dx == 2) v -= s[3];
    if (dy == 0 && dx == 0) v += s[8];
    if (dy == 0 && dx == 2) v += s[7];
    if (dy == 2 && dx == 0) v += s[6];
    if (dy == 2 && dx == 2) v += s[5];
    Sp[e] = v;
  }
  __syncthreads();
  for (int e = t; e < 512; e += 256) {
    int b = e >> 6, o = e & 63;
    const float* wrow = w3 + (size_t)o * 288;
    const float* sp = Sp + b * 288;
    float s = 0.0f;
    #pragma unroll 4
    for (int k = 0; k < 288; k++) s += wrow[k] * sp[k];
    y[e] = b3[o] + s * (1.0f / 16384.0f);
  }
  __syncthreads();
  for (int e = t; e < 2048; e += 256) {
    int b = e >> 8, j = e & 255;
    float s = fb1[j];
    for (int k = 0; k < 64; k++) s += y[b * 64 + k] * fw1[j * 64 + k];
    h1[e] = s;
  }
  __syncthreads();
  for (int e = t; e < 800; e += 256) {
    int b = e / 100, i = e - 100 * b;
    float s = fb2[i];
    for (int j = 0; j < 256; j++) s += h1[b * 256 + j] * fw2[i * 256 + j];
    vs_out[e] = (s >= 0.0f) ? s : 0.01f * s;
  }
}

// fq_mask[b][h][w] = value_set[b][searchsorted(radius_set, dist(h,w), 'left').clip(0,99)]
__global__ __launch_bounds__(256) void k_mask(const float* __restrict__ vs,
                                              float* __restrict__ fq_mask) {
  int idx = blockIdx.x * 256 + threadIdx.x;
  int h = idx >> 9, w = idx & 511;
  float da = (float)h - 256.0f, db = (float)w - 256.0f;
  float dist = sqrtf(da * da + db * db);
  int lo = 0, hi = 100;
  while (lo < hi) {
    int mid = (lo + hi) >> 1;
    float r = (362.03867196751236f * (float)(mid + 1)) * 0.01f;
    if (r < dist) lo = mid + 1; else hi = mid;
  }
  int bin = lo > 99 ? 99 : lo;
  #pragma unroll
  for (int b = 0; b < 8; b++)
    fq_mask[(size_t)b * NPIX + idx] = vs[b * 100 + bin];
}

// inverse FFT over 8 rows per block, spectrum modulation fused on load.
// p<8: identical mask for both packed components -> W = m (.) Z.
// p>=8: Hermitian unpack-modulate with mirror gather (4 images only).
// Writes to xf2 (not in place): mirror reads of other blocks' rows require it.
__global__ __launch_bounds__(256) void k_ifft_rows_mod(const float2* __restrict__ xf,
                                                       float2* __restrict__ xf2,
                                                       const float* __restrict__ fq_mask) {
  __shared__ float sr[8 * FSTR], si[8 * FSTR], twr[256], twi[256];
  int t = threadIdx.x;
  int p = blockIdx.x >> 6;
  int r0 = (blockIdx.x & 63) << 3;
  init_tw(twr, twi, t);
  if (p < 8) {
    int bm = (p + 4) & 7;
    const float* mbase = fq_mask + (size_t)bm * NPIX;
    const float4* base4 = (const float4*)(xf + (size_t)p * NPIX + (size_t)r0 * 512);
    for (int e = t; e < 2048; e += 256) {
      int u = (e & 3) | (((e >> 2) & 15) << 3) | (((e >> 6) & 1) << 2) | (((e >> 7) & 1) << 7);
      int row = e >> 8;
      float4 f = base4[row * 256 + u];
      int p0 = 2 * u;
      const float* mrow = mbase + (size_t)((r0 + row + 256) & 511) * 512;
      float2 m = *(const float2*)(mrow + ((p0 + 256) & 511));
      int rr0 = brev9(p0);
      float* cr = sr + row * FSTR;
      float* ci = si + row * FSTR;
      cr[rr0]       = f.x * m.x;  ci[rr0]       = f.y * m.x;
      cr[rr0 + 256] = f.z * m.y;  ci[rr0 + 256] = f.w * m.y;
    }
  } else {
    int k = p - 8;
    const float* fa = fq_mask + (size_t)((2 * k + 4) & 7) * NPIX;
    const float* fb = fq_mask + (size_t)((2 * k + 5) & 7) * NPIX;
    const float2* Z = xf + (size_t)p * NPIX;
    for (int e = t; e < 2048; e += 256) {
      int row = e >> 8;
      int gr = r0 + row;
      int c0 = (e & 255) * 2;
      float4 z01 = *(const float4*)(Z + (size_t)gr * 512 + c0);
      int mr = (512 - gr) & 511;
      float2 zm0 = Z[(size_t)mr * 512 + ((512 - c0) & 511)];
      float2 zm1 = Z[(size_t)mr * 512 + (511 - c0)];
      size_t mro = (size_t)((gr + 256) & 511) * 512;
      int mc = (c0 + 256) & 511;
      float2 ma = *(const float2*)(fa + mro + mc);
      float2 mb = *(const float2*)(fb + mro + mc);
      // W[k] = 0.5[(ma+mb) Z[k] + (ma-mb) conj(Z[-k])]
      float s0 = 0.5f * (ma.x + mb.x), d0 = 0.5f * (ma.x - mb.x);
      float s1 = 0.5f * (ma.y + mb.y), d1 = 0.5f * (ma.y - mb.y);
      float wr0 = s0 * z01.x + d0 * zm0.x;
      float wi0 = s0 * z01.y - d0 * zm0.y;
      float wr1 = s1 * z01.z + d1 * zm1.x;
      float wi1 = s1 * z01.w - d1 * zm1.y;
      int rr0 = brev9(c0);
      float* cr = sr + row * FSTR;
      float* ci = si + row * FSTR;
      cr[rr0]       = wr0;  ci[rr0]       = wi0;
      cr[rr0 + 256] = wr1;  ci[rr0 + 256] = wi1;
    }
  }
  fft512x8<false>(sr, si, twr, twi, t);
  float4* o4 = (float4*)(xf2 + (size_t)p * NPIX + (size_t)r0 * 512);
  for (int e = t; e < 2048; e += 256) {
    int row = e >> 8, u = e & 255;
    const float* cr = sr + row * FSTR;
    const float* ci = si + row * FSTR;
    o4[e] = make_float4(cr[2 * u], ci[2 * u], cr[2 * u + 1], ci[2 * u + 1]);
  }
}

// inverse FFT over 8 columns per block, scale 1/N, clip.
// Re -> lowpass image A, Im -> lowpass image B of the packed pair.
__global__ __launch_bounds__(256) void k_ifft_cols_out(const float2* __restrict__ xf2,
                                                       float* __restrict__ lowpass) {
  __shared__ float sr[8 * FSTR], si[8 * FSTR], twr[256], twi[256];
  int t = threadIdx.x;
  int p = blockIdx.x >> 6;
  int c0 = (blockIdx.x & 63) << 3;
  init_tw(twr, twi, t);
  const float2* base = xf2 + (size_t)p * NPIX + c0;
  const int q = t & 3;
  const int j = (t >> 2) & 15;
  const int w = t >> 6;
  #pragma unroll
  for (int it = 0; it < 8; it++) {
    int row = 32 * j + 4 * it + w;
    float4 f = *(const float4*)(base + (size_t)row * 512 + 2 * q);
    int rr = brev9(row);
    sr[(2 * q) * FSTR + rr]     = f.x;  si[(2 * q) * FSTR + rr]     = f.y;
    sr[(2 * q + 1) * FSTR + rr] = f.z;  si[(2 * q + 1) * FSTR + rr] = f.w;
  }
  fft512x8<false>(sr, si, twr, twi, t);
  const float sc = 1.0f / 262144.0f;
  int ia, ib;
  pair_src(p, ia, ib);
  float* oa = lowpass + (size_t)ia * NPIX + c0;
  float* ob = lowpass + (size_t)ib * NPIX + c0;
  const int rg = t >> 2;
  #pragma unroll
  for (int it = 0; it < 8; it++) {
    int row = 64 * it + rg;
    float re0 = sr[(2 * q) * FSTR + row],     im0 = si[(2 * q) * FSTR + row];
    float re1 = sr[(2 * q + 1) * FSTR + row], im1 = si[(2 * q + 1) * FSTR + row];
    float a0 = fminf(fmaxf(re0 * sc, 0.0f), 1.0f);
    float a1 = fminf(fmaxf(re1 * sc, 0.0f), 1.0f);
    float b0 = fminf(fmaxf(im0 * sc, 0.0f), 1.0f);
    float b1 = fminf(fmaxf(im1 * sc, 0.0f), 1.0f);
    *(float2*)(oa + (size_t)row * 512 + 2 * q) = make_float2(a0, a1);
    *(float2*)(ob + (size_t)row * 512 + 2 * q) = make_float2(b0, b1);
  }
}

extern "C" void kernel_launch(void* const* d_in, const int* in_sizes, int n_in,
                              void* d_out, int out_size, void* d_ws, size_t ws_size,
                              hipStream_t stream) {
  const float* x   = (const float*)d_in[0];
  const float* w1  = (const float*)d_in[1];
  const float* b1  = (const float*)d_in[2];
  const float* w2  = (const float*)d_in[3];
  const float* b2  = (const float*)d_in[4];
  const float* w3  = (const float*)d_in[5];
  const float* b3  = (const float*)d_in[6];
  const float* fw1 = (const float*)d_in[7];
  const float* fb1 = (const float*)d_in[8];
  const float* fw2 = (const float*)d_in[9];
  const float* fb2 = (const float*)d_in[10];

  float* lowpass = (float*)d_out;            // 8*3*512*512
  float* fq_mask = lowpass + 6291456;        // 8*512*512
  float* vs      = fq_mask + 2097152;        // 8*100

  float* base    = (float*)d_ws;
  float2* xf     = (float2*)base;            // packed spectra: 12 * 262144 c64
  float2* xf2    = (float2*)(base + 6291456);// ifft row-pass intermediate
  float* xmag    = base + 12582912;          // 6291456 floats (24 images)
  float* pooled1 = xmag + 6291456;           // 8388608 floats
  float* S       = pooled1 + 8388608;        // 8*32*9 = 2304 floats

  k_fft_rows<<<dim3(12 * 64), 256, 0, stream>>>(x, xf);
  k_fft_cols<<<dim3(12 * 64), 256, 0, stream>>>(xf);
  k_xmag<<<dim3(12 * 64), 256, 0, stream>>>(xf, xmag);

  k_conv1<<<dim3(4, 32, 16), 256, 0, stream>>>(x, xmag, w1, b1, pooled1);
  hipMemsetAsync(S, 0, 2304 * sizeof(float), stream);
  k_conv2<<<dim3(4, 16, 32), 256, 0, stream>>>(pooled1, w2, b2, S);

  k_fc<<<1, 256, 0, stream>>>(S, w3, b3, fw1, fb1, fw2, fb2, vs);
  k_mask<<<1024, 256, 0, stream>>>(vs, fq_mask);

  k_ifft_rows_mod<<<dim3(12 * 64), 256, 0, stream>>>(xf, xf2, fq_mask);
  k_ifft_cols_out<<<dim3(12 * 64), 256, 0, stream>>>(xf2, lowpass);
}

// Round 5
// 358.104 us; speedup vs baseline: 1.8811x; 1.8811x over previous
//
#include <hip/hip_runtime.h>
#include <math.h>

#define NPIX 262144   // 512*512
#define FSTR 513      // LDS column stride for batch-8 FFT (pad 512+1)

typedef __attribute__((ext_vector_type(2))) float v2f;

// ---------------------------------------------------------------------------
// Complex-packing scheme: 24 real images -> 12 packed complex images.
//   p in [0,8):  z = x[b=p, c=0] + i * x[b=p, c=1]   (same per-batch mask!)
//   p in [8,12): k=p-8, z = x[b=2k, c=2] + i * x[b=2k+1, c=2] (masks differ)
// Forward 2D FFT, modulation, inverse 2D FFT all operate on packed z:
//   - pairs p<8: masked spectrum = m (.) Z  (mask identical for Re/Im parts)
//   - pairs p>=8: W[k] = 0.5[(ma+mb) Z[k] + (ma-mb) conj(Z[-k])] (Hermitian)
//   - lowpass_A = clip(Re(ifft W)), lowpass_B = clip(Im(ifft W))
//   - xmag needs explicit Hermitian unpack -> separate k_xmag kernel.
// ---------------------------------------------------------------------------

__device__ __forceinline__ int brev9(int i) { return (int)(__brev((unsigned)i) >> 23); }

// Intra-wave LDS fence: column data deps in fft512x8 are wave-internal
// (column c is owned by threads 32c..32c+31; 2 columns per wave64), so the
// interior stage barriers need only DS-completion ordering, not a workgroup
// barrier. "memory" clobber stops compiler reordering LDS ops across it.
__device__ __forceinline__ void wave_lds_fence() {
  asm volatile("s_waitcnt lgkmcnt(0)" ::: "memory");
}

__device__ __forceinline__ void init_tw(float* twr, float* twi, int t) {
  if (t < 256) {
    float ang = -3.14159265358979323846f * (float)t / 256.0f;
    float s, c;
    sincosf(ang, &s, &c);
    twr[t] = c; twi[t] = s;
  }
}

// 8 x 512-pt FFTs in LDS, column-major: element p of FFT c at [c*FSTR + p].
// Radix-4 core, final radix-2 stage. Input stored radix-2 bit-reversed.
// Barriers: only the FIRST (after cross-wave staging) and LAST (before
// cross-wave output read) are workgroup barriers; interior syncs are
// intra-wave lgkmcnt fences (column-private deps).
template<bool FWD>
__device__ __forceinline__ void fft512x8(float* __restrict__ sr, float* __restrict__ si,
                                         const float* __restrict__ twr,
                                         const float* __restrict__ twi, int t) {
  const int c  = t >> 5;
  const int tq = t & 31;
  float* cr = sr + c * FSTR;
  float* ci = si + c * FSTR;
  #pragma unroll
  for (int sp = 0; sp < 4; sp++) {
    const int s = 2 * sp;
    const int h = 1 << s;
    if (sp == 0) __syncthreads(); else wave_lds_fence();
    #pragma unroll
    for (int m = 0; m < 4; m++) {
      int q = tq + 32 * m;                    // quad id 0..127
      int j = q & (h - 1);
      int base = ((q >> s) << (s + 2)) | j;
      int i1 = j << (8 - s);                  // stage-s twiddle
      int i2 = j << (7 - s);                  // stage-(s+1) twiddle
      float w1r = twr[i1], w1i = FWD ? twi[i1] : -twi[i1];
      float w2r = twr[i2], w2i = FWD ? twi[i2] : -twi[i2];
      float ar = cr[base],         ai = ci[base];
      float br = cr[base + h],     bi = ci[base + h];
      float c2r = cr[base + 2*h],  c2i = ci[base + 2*h];
      float dr = cr[base + 3*h],   di = ci[base + 3*h];
      // stage s
      float wbr = br * w1r - bi * w1i, wbi = br * w1i + bi * w1r;
      float wdr = dr * w1r - di * w1i, wdi = dr * w1i + di * w1r;
      float t0r = ar + wbr,  t0i = ai + wbi;
      float t1r = ar - wbr,  t1i = ai - wbi;
      float t2r = c2r + wdr, t2i = c2i + wdi;
      float t3r = c2r - wdr, t3i = c2i - wdi;
      // stage s+1 ; w2' = w2 * (-i) fwd, (+i) inv
      float u2r = t2r * w2r - t2i * w2i, u2i = t2r * w2i + t2i * w2r;
      float v3r = t3r * w2r - t3i * w2i, v3i = t3r * w2i + t3i * w2r;
      float u3r = FWD ? v3i : -v3i;
      float u3i = FWD ? -v3r : v3r;
      cr[base]         = t0r + u2r;  ci[base]         = t0i + u2i;
      cr[base + 2*h]   = t0r - u2r;  ci[base + 2*h]   = t0i - u2i;
      cr[base + h]     = t1r + u3r;  ci[base + h]     = t1i + u3i;
      cr[base + 3*h]   = t1r - u3r;  ci[base + 3*h]   = t1i - u3i;
    }
  }
  // final radix-2 stage (s=8, half=256)
  wave_lds_fence();
  #pragma unroll
  for (int m = 0; m < 8; m++) {
    int k = tq + 32 * m;                      // 0..255 == j
    float wr = twr[k], wi = FWD ? twi[k] : -twi[k];
    float vr = cr[k + 256], vi = ci[k + 256];
    float tr = vr * wr - vi * wi;
    float ti = vr * wi + vi * wr;
    float ur = cr[k], ui = ci[k];
    cr[k] = ur + tr;        ci[k] = ui + ti;
    cr[k + 256] = ur - tr;  ci[k + 256] = ui - ti;
  }
  __syncthreads();
}

// pair tables (device-side from p)
__device__ __forceinline__ void pair_src(int p, int& ia, int& ib) {
  if (p < 8) { ia = 3 * p; ib = 3 * p + 1; }
  else { int k = p - 8; ia = 6 * k + 2; ib = 6 * k + 5; }
}

// forward FFT over 8 contiguous rows per block; packs two real images.
__global__ __launch_bounds__(256) void k_fft_rows(const float* __restrict__ x,
                                                  float2* __restrict__ xf) {
  __shared__ float sr[8 * FSTR], si[8 * FSTR], twr[256], twi[256];
  int t = threadIdx.x;
  int p = blockIdx.x >> 6;
  int r0 = (blockIdx.x & 63) << 3;
  init_tw(twr, twi, t);
  int ia, ib;
  pair_src(p, ia, ib);
  const float4* pa = (const float4*)(x + (size_t)ia * NPIX + (size_t)r0 * 512);
  const float4* pb = (const float4*)(x + (size_t)ib * NPIX + (size_t)r0 * 512);
  for (int e = t; e < 1024; e += 256) {
    int row = e >> 7, w = e & 127;
    float4 fa = pa[e];
    float4 fb = pb[e];
    float* cr = sr + row * FSTR;
    float* ci = si + row * FSTR;
    int pc = 4 * w;
    cr[brev9(pc)]     = fa.x;  ci[brev9(pc)]     = fb.x;
    cr[brev9(pc + 1)] = fa.y;  ci[brev9(pc + 1)] = fb.y;
    cr[brev9(pc + 2)] = fa.z;  ci[brev9(pc + 2)] = fb.z;
    cr[brev9(pc + 3)] = fa.w;  ci[brev9(pc + 3)] = fb.w;
  }
  fft512x8<true>(sr, si, twr, twi, t);
  float4* q4 = (float4*)(xf + (size_t)p * NPIX + (size_t)r0 * 512);
  for (int e = t; e < 2048; e += 256) {
    int row = e >> 8, u = e & 255;
    const float* cr = sr + row * FSTR;
    const float* ci = si + row * FSTR;
    q4[e] = make_float4(cr[2 * u], ci[2 * u], cr[2 * u + 1], ci[2 * u + 1]);
  }
}

// forward FFT over 8 adjacent columns per block (in-place on packed xf).
__global__ __launch_bounds__(256) void k_fft_cols(float2* __restrict__ xf) {
  __shared__ float sr[8 * FSTR], si[8 * FSTR], twr[256], twi[256];
  int t = threadIdx.x;
  int p = blockIdx.x >> 6;
  int c0 = (blockIdx.x & 63) << 3;
  init_tw(twr, twi, t);
  float2* base = xf + (size_t)p * NPIX + c0;
  const int q = t & 3;
  const int j = (t >> 2) & 15;
  const int w = t >> 6;
  #pragma unroll
  for (int it = 0; it < 8; it++) {
    int row = 32 * j + 4 * it + w;           // stride-32 row set
    float4 f = *(const float4*)(base + (size_t)row * 512 + 2 * q);
    int rr = brev9(row);
    sr[(2 * q) * FSTR + rr]     = f.x;  si[(2 * q) * FSTR + rr]     = f.y;
    sr[(2 * q + 1) * FSTR + rr] = f.z;  si[(2 * q + 1) * FSTR + rr] = f.w;
  }
  fft512x8<true>(sr, si, twr, twi, t);
  const int rg = t >> 2;                     // 0..63
  #pragma unroll
  for (int it = 0; it < 8; it++) {
    int row = 64 * it + rg;                  // consecutive row set
    float a0 = sr[(2 * q) * FSTR + row],     b0 = si[(2 * q) * FSTR + row];
    float a1 = sr[(2 * q + 1) * FSTR + row], b1 = si[(2 * q + 1) * FSTR + row];
    *(float4*)(base + (size_t)row * 512 + 2 * q) = make_float4(a0, b0, a1, b1);
  }
}

// Hermitian unpack of packed spectra -> log-magnitudes for both components,
// scattered to the fftshift-remapped xmag slots (batch +4, channel +1, and
// spatial ^256 shift) that conv1 consumes.
__global__ __launch_bounds__(256) void k_xmag(const float2* __restrict__ xf,
                                              float* __restrict__ xmag) {
  int t = threadIdx.x;
  int p = blockIdx.x >> 6;
  int r0 = (blockIdx.x & 63) << 3;
  int da, db;
  if (p < 8) {
    int bs = (p + 4) & 7;
    da = bs * 3 + 1;                 // (b,0) -> slot (b+4, 1)
    db = bs * 3 + 2;                 // (b,1) -> slot (b+4, 2)
  } else {
    int k = p - 8;
    da = ((2 * k + 4) & 7) * 3;      // (2k,2)   -> slot (2k+4, 0)
    db = ((2 * k + 5) & 7) * 3;      // (2k+1,2) -> slot (2k+5, 0)
  }
  const float2* Z = xf + (size_t)p * NPIX;
  float* A = xmag + (size_t)da * NPIX;
  float* B = xmag + (size_t)db * NPIX;
  for (int e = t; e < 2048; e += 256) {
    int row = r0 + (e >> 8);
    int c0 = (e & 255) * 2;
    float4 z01 = *(const float4*)(Z + (size_t)row * 512 + c0);
    int mr = (512 - row) & 511;
    float2 zm0 = Z[(size_t)mr * 512 + ((512 - c0) & 511)];
    float2 zm1 = Z[(size_t)mr * 512 + (511 - c0)];
    // X_A = (Z + conj(Zm))/2 ; |X_B| = |Z - conj(Zm)|/2
    float ar0 = 0.5f * (z01.x + zm0.x), ai0 = 0.5f * (z01.y - zm0.y);
    float br0 = 0.5f * (z01.x - zm0.x), bi0 = 0.5f * (z01.y + zm0.y);
    float ar1 = 0.5f * (z01.z + zm1.x), ai1 = 0.5f * (z01.w - zm1.y);
    float br1 = 0.5f * (z01.z - zm1.x), bi1 = 0.5f * (z01.w + zm1.y);
    float ma0 = log10f(sqrtf(ar0 * ar0 + ai0 * ai0) + 1.0f);
    float ma1 = log10f(sqrtf(ar1 * ar1 + ai1 * ai1) + 1.0f);
    float mb0 = log10f(sqrtf(br0 * br0 + bi0 * bi0) + 1.0f);
    float mb1 = log10f(sqrtf(br1 * br1 + bi1 * bi1) + 1.0f);
    size_t off = (size_t)(row ^ 256) * 512 + (c0 ^ 256);
    *(float2*)(A + off) = make_float2(ma0, ma1);
    *(float2*)(B + off) = make_float2(mb0, mb1);
  }
}

// conv1: 6->16, 512x512, pad1, relu, 2x2 avgpool -> [b][16][256][256]
// grid (4, 32, 16). Double-buffered, ONE barrier per ic. Packed-fp32 FMA.
// (R4's distance-2 prefetch reverted: it ballooned VGPR 40->220.)
__global__ __launch_bounds__(256) void k_conv1(const float* __restrict__ x,
                                               const float* __restrict__ xmag,
                                               const float* __restrict__ w1,
                                               const float* __restrict__ b1,
                                               float* __restrict__ out) {
  __shared__ float tile[2][18 * 132 + 8];
  const int t = threadIdx.x;
  const int tx = t & 31, ty = t >> 5;
  const int PC0 = blockIdx.x * 64;
  const int PR0 = blockIdx.y * 8;
  const int b  = blockIdx.z >> 1;
  const int og = (blockIdx.z & 1) * 8;
  const int R0 = PR0 * 2 - 1;
  const int C0 = PC0 * 2 - 1;

  int li[10], gi[10];
  bool okf[10];
  #pragma unroll
  for (int k = 0; k < 10; k++) {
    int e = t + 256 * k;
    bool valid = e < 2340;
    int i = e / 130, j = e - i * 130;
    int rr = R0 + i, cc = C0 + j;
    bool ok = valid && ((unsigned)rr < 512u) && ((unsigned)cc < 512u);
    li[k] = valid ? (i * 132 + j) : (18 * 132);
    gi[k] = ok ? (rr * 512 + cc) : 0;
    okf[k] = ok;
  }

  v2f acc[8][4];
  #pragma unroll
  for (int o = 0; o < 8; o++)
    #pragma unroll
    for (int q = 0; q < 4; q++) acc[o][q] = (v2f){0.0f, 0.0f};

  const float* xb = x + (size_t)(b * 3) * NPIX;
  const float* mb = xmag + (size_t)(b * 3) * NPIX;

  float ld[10];
  #pragma unroll
  for (int k = 0; k < 10; k++) ld[k] = okf[k] ? xb[gi[k]] : 0.0f;
  #pragma unroll
  for (int k = 0; k < 10; k++) tile[0][li[k]] = ld[k];
  __syncthreads();

  for (int ic = 0; ic < 6; ic++) {
    if (ic < 5) {
      const float* sn = (ic + 1 < 3) ? (xb + (size_t)(ic + 1) * NPIX)
                                     : (mb + (size_t)(ic - 2) * NPIX);
      #pragma unroll
      for (int k = 0; k < 10; k++) ld[k] = okf[k] ? sn[gi[k]] : 0.0f;
    }
    const float* cur = tile[ic & 1];
    float patch[4][6];
    #pragma unroll
    for (int dy = 0; dy < 4; dy++) {
      const float* rp = cur + (2 * ty + dy) * 132 + 4 * tx;
      float4 f = *(const float4*)rp;
      float2 g = *(const float2*)(rp + 4);
      patch[dy][0] = f.x; patch[dy][1] = f.y; patch[dy][2] = f.z;
      patch[dy][3] = f.w; patch[dy][4] = g.x; patch[dy][5] = g.y;
    }
    v2f pr[4][5];
    #pragma unroll
    for (int dy = 0; dy < 4; dy++)
      #pragma unroll
      for (int s = 0; s < 5; s++)
        pr[dy][s] = (v2f){patch[dy][s], patch[dy][s + 1]};
    #pragma unroll
    for (int o = 0; o < 8; o++) {
      const float* wk = w1 + (size_t)((og + o) * 6 + ic) * 9;
      #pragma unroll
      for (int dy = 0; dy < 3; dy++)
        #pragma unroll
        for (int kc = 0; kc < 3; kc++) {
          float kw = wk[dy * 3 + kc];
          v2f wv = (v2f){kw, kw};
          acc[o][0] += wv * pr[dy][kc];
          acc[o][1] += wv * pr[dy][kc + 2];
          acc[o][2] += wv * pr[dy + 1][kc];
          acc[o][3] += wv * pr[dy + 1][kc + 2];
        }
    }
    if (ic < 5) {
      float* nxt = tile[(ic + 1) & 1];
      #pragma unroll
      for (int k = 0; k < 10; k++) nxt[li[k]] = ld[k];
      __syncthreads();
    }
  }
  #pragma unroll
  for (int o = 0; o < 8; o++) {
    float bias = b1[og + o];
    float p0 = fmaxf(acc[o][0].x + bias, 0.0f) + fmaxf(acc[o][0].y + bias, 0.0f)
             + fmaxf(acc[o][2].x + bias, 0.0f) + fmaxf(acc[o][2].y + bias, 0.0f);
    float p1 = fmaxf(acc[o][1].x + bias, 0.0f) + fmaxf(acc[o][1].y + bias, 0.0f)
             + fmaxf(acc[o][3].x + bias, 0.0f) + fmaxf(acc[o][3].y + bias, 0.0f);
    float2* q = (float2*)(out + ((size_t)(b * 16 + og + o) * 256 + PR0 + ty) * 256 + PC0 + 2 * tx);
    *q = make_float2(p0 * 0.25f, p1 * 0.25f);
  }
}

// conv2: 16->32, 256x256, pad1, relu, pool -> 9 stats per (b,oc) -> S[b][32][9].
// grid (4, 16, 32), og=8 per block; packed-fp32 inner loop.
__global__ __launch_bounds__(256) void k_conv2(const float* __restrict__ in,
                                               const float* __restrict__ w2,
                                               const float* __restrict__ b2,
                                               float* __restrict__ S) {
  __shared__ float tile[2][18 * 68 + 8];
  __shared__ float wsum[4][8];
  const int t = threadIdx.x;
  const int tx = t & 31, ty = t >> 5;
  const int bx = blockIdx.x, by = blockIdx.y;
  const int PC0 = bx * 32;
  const int PR0 = by * 8;
  const int b  = blockIdx.z >> 2;
  const int og = (blockIdx.z & 3) * 8;
  const int R0 = PR0 * 2 - 1;
  const int C0 = PC0 * 2 - 1;

  int li[5], gi[5];
  bool okf[5];
  #pragma unroll
  for (int k = 0; k < 5; k++) {
    int e = t + 256 * k;
    bool valid = e < 1188;
    int i = e / 66, j = e - 66 * i;
    int rr = R0 + i, cc = C0 + j;
    bool ok = valid && ((unsigned)rr < 256u) && ((unsigned)cc < 256u);
    li[k] = valid ? (i * 68 + j) : (18 * 68);
    gi[k] = ok ? (rr * 256 + cc) : 0;
    okf[k] = ok;
  }

  v2f acc[8][2];
  #pragma unroll
  for (int o = 0; o < 8; o++) {
    acc[o][0] = (v2f){0.0f, 0.0f};
    acc[o][1] = (v2f){0.0f, 0.0f};
  }

  const float* inb = in + (size_t)(b * 16) * 65536;

  float ld[5];
  #pragma unroll
  for (int k = 0; k < 5; k++) ld[k] = okf[k] ? inb[gi[k]] : 0.0f;
  #pragma unroll
  for (int k = 0; k < 5; k++) tile[0][li[k]] = ld[k];
  __syncthreads();

  for (int ic = 0; ic < 16; ic++) {
    if (ic < 15) {
      const float* sn = inb + (size_t)(ic + 1) * 65536;
      #pragma unroll
      for (int k = 0; k < 5; k++) ld[k] = okf[k] ? sn[gi[k]] : 0.0f;
    }
    const float* cur = tile[ic & 1];
    float patch[4][4];
    #pragma unroll
    for (int dy = 0; dy < 4; dy++) {
      const float* rp = cur + (2 * ty + dy) * 68 + 2 * tx;
      float2 f0 = *(const float2*)rp;
      float2 f1 = *(const float2*)(rp + 2);
      patch[dy][0] = f0.x; patch[dy][1] = f0.y;
      patch[dy][2] = f1.x; patch[dy][3] = f1.y;
    }
    v2f pr[4][3];
    #pragma unroll
    for (int dy = 0; dy < 4; dy++) {
      pr[dy][0] = (v2f){patch[dy][0], patch[dy][1]};
      pr[dy][1] = (v2f){patch[dy][1], patch[dy][2]};
      pr[dy][2] = (v2f){patch[dy][2], patch[dy][3]};
    }
    #pragma unroll
    for (int o = 0; o < 8; o++) {
      const float* wk = w2 + (size_t)((og + o) * 16 + ic) * 9;
      #pragma unroll
      for (int dy = 0; dy < 3; dy++)
        #pragma unroll
        for (int kc = 0; kc < 3; kc++) {
          float kw = wk[dy * 3 + kc];
          v2f wv = (v2f){kw, kw};
          acc[o][0] += wv * pr[dy][kc];
          acc[o][1] += wv * pr[dy + 1][kc];
        }
    }
    if (ic < 15) {
      float* nxt = tile[(ic + 1) & 1];
      #pragma unroll
      for (int k = 0; k < 5; k++) nxt[li[k]] = ld[k];
      __syncthreads();
    }
  }

  const int lane = t & 63;
  const int wid = t >> 6;
  float* Sb0 = S + (size_t)(b * 32 + og) * 9;
  #pragma unroll
  for (int o = 0; o < 8; o++) {
    float bias = b2[og + o];
    float v = (fmaxf(acc[o][0].x + bias, 0.0f) + fmaxf(acc[o][0].y + bias, 0.0f)
             + fmaxf(acc[o][1].x + bias, 0.0f) + fmaxf(acc[o][1].y + bias, 0.0f)) * 0.25f;
    float* Sb = Sb0 + o * 9;
    float ts = v;
    #pragma unroll
    for (int off = 32; off > 0; off >>= 1) ts += __shfl_down(ts, off);
    if (lane == 0) wsum[wid][o] = ts;
    if (by == 0) {
      float e = (ty == 0) ? v : 0.0f;
      #pragma unroll
      for (int off = 32; off > 0; off >>= 1) e += __shfl_down(e, off);
      if (lane == 0) atomicAdd(&Sb[1], e);
    }
    if (by == 15) {
      float e = (ty == 7) ? v : 0.0f;
      #pragma unroll
      for (int off = 32; off > 0; off >>= 1) e += __shfl_down(e, off);
      if (lane == 0) atomicAdd(&Sb[2], e);
    }
    if (bx == 0 && tx == 0)  atomicAdd(&Sb[3], v);
    if (bx == 3 && tx == 31) atomicAdd(&Sb[4], v);
    if (bx == 0 && by == 0  && t == 0)   Sb[5] = v;
    if (bx == 3 && by == 0  && t == 31)  Sb[6] = v;
    if (bx == 0 && by == 15 && t == 224) Sb[7] = v;
    if (bx == 3 && by == 15 && t == 255) Sb[8] = v;
  }
  __syncthreads();
  if (t < 8)
    atomicAdd(&Sb0[t * 9], wsum[0][t] + wsum[1][t] + wsum[2][t] + wsum[3][t]);
}

// k_fc: stats -> conv3-mean (matvec over 288 window sums) -> FC1 -> FC2 -> leaky.
__global__ __launch_bounds__(256) void k_fc(const float* __restrict__ S,
                                            const float* __restrict__ w3,
                                            const float* __restrict__ b3,
                                            const float* __restrict__ fw1,
                                            const float* __restrict__ fb1,
                                            const float* __restrict__ fw2,
                                            const float* __restrict__ fb2,
                                            float* __restrict__ vs_out) {
  __shared__ float Sp[2304];
  __shared__ float y[512];
  __shared__ float h1[2048];
  int t = threadIdx.x;
  for (int e = t; e < 2304; e += 256) {
    int cell = e / 9, k = e - 9 * cell;
    int dy = k / 3, dx = k - 3 * dy;
    const float* s = S + cell * 9;
    float v = s[0];
    if (dy == 0) v -= s[2];
    if (dy == 2) v -= s[1];
    if (dx == 0) v -= s[4];
    if (dx == 2) v -= s[3];
    if (dy == 0 && dx == 0) v += s[8];
    if (dy == 0 && dx == 2) v += s[7];
    if (dy == 2 && dx == 0) v += s[6];
    if (dy == 2 && dx == 2) v += s[5];
    Sp[e] = v;
  }
  __syncthreads();
  for (int e = t; e < 512; e += 256) {
    int b = e >> 6, o = e & 63;
    const float* wrow = w3 + (size_t)o * 288;
    const float* sp = Sp + b * 288;
    float s = 0.0f;
    #pragma unroll 4
    for (int k = 0; k < 288; k++) s += wrow[k] * sp[k];
    y[e] = b3[o] + s * (1.0f / 16384.0f);
  }
  __syncthreads();
  for (int e = t; e < 2048; e += 256) {
    int b = e >> 8, j = e & 255;
    float s = fb1[j];
    for (int k = 0; k < 64; k++) s += y[b * 64 + k] * fw1[j * 64 + k];
    h1[e] = s;
  }
  __syncthreads();
  for (int e = t; e < 800; e += 256) {
    int b = e / 100, i = e - 100 * b;
    float s = fb2[i];
    for (int j = 0; j < 256; j++) s += h1[b * 256 + j] * fw2[i * 256 + j];
    vs_out[e] = (s >= 0.0f) ? s : 0.01f * s;
  }
}

// fq_mask[b][h][w] = value_set[b][searchsorted(radius_set, dist(h,w), 'left').clip(0,99)]
__global__ __launch_bounds__(256) void k_mask(const float* __restrict__ vs,
                                              float* __restrict__ fq_mask) {
  int idx = blockIdx.x * 256 + threadIdx.x;
  int h = idx >> 9, w = idx & 511;
  float da = (float)h - 256.0f, db = (float)w - 256.0f;
  float dist = sqrtf(da * da + db * db);
  int lo = 0, hi = 100;
  while (lo < hi) {
    int mid = (lo + hi) >> 1;
    float r = (362.03867196751236f * (float)(mid + 1)) * 0.01f;
    if (r < dist) lo = mid + 1; else hi = mid;
  }
  int bin = lo > 99 ? 99 : lo;
  #pragma unroll
  for (int b = 0; b < 8; b++)
    fq_mask[(size_t)b * NPIX + idx] = vs[b * 100 + bin];
}

// inverse FFT over 8 rows per block, spectrum modulation fused on load.
// p<8: identical mask for both packed components -> W = m (.) Z.
// p>=8: Hermitian unpack-modulate with mirror gather (4 images only).
// Writes to xf2 (not in place): mirror reads of other blocks' rows require it.
__global__ __launch_bounds__(256) void k_ifft_rows_mod(const float2* __restrict__ xf,
                                                       float2* __restrict__ xf2,
                                                       const float* __restrict__ fq_mask) {
  __shared__ float sr[8 * FSTR], si[8 * FSTR], twr[256], twi[256];
  int t = threadIdx.x;
  int p = blockIdx.x >> 6;
  int r0 = (blockIdx.x & 63) << 3;
  init_tw(twr, twi, t);
  if (p < 8) {
    int bm = (p + 4) & 7;
    const float* mbase = fq_mask + (size_t)bm * NPIX;
    const float4* base4 = (const float4*)(xf + (size_t)p * NPIX + (size_t)r0 * 512);
    for (int e = t; e < 2048; e += 256) {
      int u = (e & 3) | (((e >> 2) & 15) << 3) | (((e >> 6) & 1) << 2) | (((e >> 7) & 1) << 7);
      int row = e >> 8;
      float4 f = base4[row * 256 + u];
      int p0 = 2 * u;
      const float* mrow = mbase + (size_t)((r0 + row + 256) & 511) * 512;
      float2 m = *(const float2*)(mrow + ((p0 + 256) & 511));
      int rr0 = brev9(p0);
      float* cr = sr + row * FSTR;
      float* ci = si + row * FSTR;
      cr[rr0]       = f.x * m.x;  ci[rr0]       = f.y * m.x;
      cr[rr0 + 256] = f.z * m.y;  ci[rr0 + 256] = f.w * m.y;
    }
  } else {
    int k = p - 8;
    const float* fa = fq_mask + (size_t)((2 * k + 4) & 7) * NPIX;
    const float* fb = fq_mask + (size_t)((2 * k + 5) & 7) * NPIX;
    const float2* Z = xf + (size_t)p * NPIX;
    for (int e = t; e < 2048; e += 256) {
      int row = e >> 8;
      int gr = r0 + row;
      int c0 = (e & 255) * 2;
      float4 z01 = *(const float4*)(Z + (size_t)gr * 512 + c0);
      int mr = (512 - gr) & 511;
      float2 zm0 = Z[(size_t)mr * 512 + ((512 - c0) & 511)];
      float2 zm1 = Z[(size_t)mr * 512 + (511 - c0)];
      size_t mro = (size_t)((gr + 256) & 511) * 512;
      int mc = (c0 + 256) & 511;
      float2 ma = *(const float2*)(fa + mro + mc);
      float2 mb = *(const float2*)(fb + mro + mc);
      // W[k] = 0.5[(ma+mb) Z[k] + (ma-mb) conj(Z[-k])]
      float s0 = 0.5f * (ma.x + mb.x), d0 = 0.5f * (ma.x - mb.x);
      float s1 = 0.5f * (ma.y + mb.y), d1 = 0.5f * (ma.y - mb.y);
      float wr0 = s0 * z01.x + d0 * zm0.x;
      float wi0 = s0 * z01.y - d0 * zm0.y;
      float wr1 = s1 * z01.z + d1 * zm1.x;
      float wi1 = s1 * z01.w - d1 * zm1.y;
      int rr0 = brev9(c0);
      float* cr = sr + row * FSTR;
      float* ci = si + row * FSTR;
      cr[rr0]       = wr0;  ci[rr0]       = wi0;
      cr[rr0 + 256] = wr1;  ci[rr0 + 256] = wi1;
    }
  }
  fft512x8<false>(sr, si, twr, twi, t);
  float4* o4 = (float4*)(xf2 + (size_t)p * NPIX + (size_t)r0 * 512);
  for (int e = t; e < 2048; e += 256) {
    int row = e >> 8, u = e & 255;
    const float* cr = sr + row * FSTR;
    const float* ci = si + row * FSTR;
    o4[e] = make_float4(cr[2 * u], ci[2 * u], cr[2 * u + 1], ci[2 * u + 1]);
  }
}

// inverse FFT over 8 columns per block, scale 1/N, clip.
// Re -> lowpass image A, Im -> lowpass image B of the packed pair.
__global__ __launch_bounds__(256) void k_ifft_cols_out(const float2* __restrict__ xf2,
                                                       float* __restrict__ lowpass) {
  __shared__ float sr[8 * FSTR], si[8 * FSTR], twr[256], twi[256];
  int t = threadIdx.x;
  int p = blockIdx.x >> 6;
  int c0 = (blockIdx.x & 63) << 3;
  init_tw(twr, twi, t);
  const float2* base = xf2 + (size_t)p * NPIX + c0;
  const int q = t & 3;
  const int j = (t >> 2) & 15;
  const int w = t >> 6;
  #pragma unroll
  for (int it = 0; it < 8; it++) {
    int row = 32 * j + 4 * it + w;
    float4 f = *(const float4*)(base + (size_t)row * 512 + 2 * q);
    int rr = brev9(row);
    sr[(2 * q) * FSTR + rr]     = f.x;  si[(2 * q) * FSTR + rr]     = f.y;
    sr[(2 * q + 1) * FSTR + rr] = f.z;  si[(2 * q + 1) * FSTR + rr] = f.w;
  }
  fft512x8<false>(sr, si, twr, twi, t);
  const float sc = 1.0f / 262144.0f;
  int ia, ib;
  pair_src(p, ia, ib);
  float* oa = lowpass + (size_t)ia * NPIX + c0;
  float* ob = lowpass + (size_t)ib * NPIX + c0;
  const int rg = t >> 2;
  #pragma unroll
  for (int it = 0; it < 8; it++) {
    int row = 64 * it + rg;
    float re0 = sr[(2 * q) * FSTR + row],     im0 = si[(2 * q) * FSTR + row];
    float re1 = sr[(2 * q + 1) * FSTR + row], im1 = si[(2 * q + 1) * FSTR + row];
    float a0 = fminf(fmaxf(re0 * sc, 0.0f), 1.0f);
    float a1 = fminf(fmaxf(re1 * sc, 0.0f), 1.0f);
    float b0 = fminf(fmaxf(im0 * sc, 0.0f), 1.0f);
    float b1 = fminf(fmaxf(im1 * sc, 0.0f), 1.0f);
    *(float2*)(oa + (size_t)row * 512 + 2 * q) = make_float2(a0, a1);
    *(float2*)(ob + (size_t)row * 512 + 2 * q) = make_float2(b0, b1);
  }
}

extern "C" void kernel_launch(void* const* d_in, const int* in_sizes, int n_in,
                              void* d_out, int out_size, void* d_ws, size_t ws_size,
                              hipStream_t stream) {
  const float* x   = (const float*)d_in[0];
  const float* w1  = (const float*)d_in[1];
  const float* b1  = (const float*)d_in[2];
  const float* w2  = (const float*)d_in[3];
  const float* b2  = (const float*)d_in[4];
  const float* w3  = (const float*)d_in[5];
  const float* b3  = (const float*)d_in[6];
  const float* fw1 = (const float*)d_in[7];
  const float* fb1 = (const float*)d_in[8];
  const float* fw2 = (const float*)d_in[9];
  const float* fb2 = (const float*)d_in[10];

  float* lowpass = (float*)d_out;            // 8*3*512*512
  float* fq_mask = lowpass + 6291456;        // 8*512*512
  float* vs      = fq_mask + 2097152;        // 8*100

  float* base    = (float*)d_ws;
  float2* xf     = (float2*)base;            // packed spectra: 12 * 262144 c64
  float2* xf2    = (float2*)(base + 6291456);// ifft row-pass intermediate
  float* xmag    = base + 12582912;          // 6291456 floats (24 images)
  float* pooled1 = xmag + 6291456;           // 8388608 floats
  float* S       = pooled1 + 8388608;        // 8*32*9 = 2304 floats

  k_fft_rows<<<dim3(12 * 64), 256, 0, stream>>>(x, xf);
  k_fft_cols<<<dim3(12 * 64), 256, 0, stream>>>(xf);
  k_xmag<<<dim3(12 * 64), 256, 0, stream>>>(xf, xmag);

  k_conv1<<<dim3(4, 32, 16), 256, 0, stream>>>(x, xmag, w1, b1, pooled1);
  hipMemsetAsync(S, 0, 2304 * sizeof(float), stream);
  k_conv2<<<dim3(4, 16, 32), 256, 0, stream>>>(pooled1, w2, b2, S);

  k_fc<<<1, 256, 0, stream>>>(S, w3, b3, fw1, fb1, fw2, fb2, vs);
  k_mask<<<1024, 256, 0, stream>>>(vs, fq_mask);

  k_ifft_rows_mod<<<dim3(12 * 64), 256, 0, stream>>>(xf, xf2, fq_mask);
  k_ifft_cols_out<<<dim3(12 * 64), 256, 0, stream>>>(xf2, lowpass);
}